// Round 1
// baseline (265.961 us; speedup 1.0000x reference)
//
#include <hip/hip_runtime.h>
#include <math.h>

// ---------------------------------------------------------------------------
// AttentionLayer: out = softmax(mask(q k^T * scale)) @ v,  q/k/v = x@W + b
// B=4, T=2048, C=H=768.  All GEMMs via bf16 MFMA (16x16x32), fp32 accumulate.
// Threshold is 2% of ref absmax -> bf16 internal precision is acceptable.
// ---------------------------------------------------------------------------

#define BB 4
#define TT 2048
#define CC 768

typedef __bf16 bf16_t;
typedef __bf16 bf16x8 __attribute__((ext_vector_type(8)));
typedef float f32x4 __attribute__((ext_vector_type(4)));

// ---------------------------------------------------------------------------
// async global->LDS 16B copy (wave-uniform LDS base + lane*16 implicit)
// ---------------------------------------------------------------------------
__device__ __forceinline__ void async_load16(void* lds, const void* g) {
  __builtin_amdgcn_global_load_lds(
      (const __attribute__((address_space(1))) void*)g,
      (__attribute__((address_space(3))) void*)lds, 16, 0, 0);
}

// Stage a 128x32 bf16 tile (row-major, row stride ld elements) into LDS.
// LDS layout: row-major 128x32, but 8-elem chunks XOR-swizzled within a row:
// physical chunk p of row r holds logical chunk p ^ (r & 3).
__device__ __forceinline__ void stage_tile(const bf16_t* __restrict__ g0,
                                           int ld, bf16_t* lds, int t) {
  int w = t >> 6, l = t & 63;
#pragma unroll
  for (int i = 0; i < 2; ++i) {
    int c = i * 256 + w * 64 + l;   // linear 16B-chunk id in LDS
    int row = c >> 2;
    int p = c & 3;
    int q = p ^ (row & 3);          // logical chunk to fetch
    async_load16(lds + i * 2048 + w * 512,  // wave-uniform base (elements)
                 g0 + row * ld + q * 8);
  }
}

// Read one MFMA fragment (8 bf16, 16B) for logical (row r, k-chunk q).
__device__ __forceinline__ bf16x8 read_frag(const bf16_t* lds, int r, int q) {
  int p = q ^ (r & 3);
  return *(const bf16x8*)(lds + r * 32 + p * 8);
}

// Core: C[128x128] += A[128xK] * B^T where Bt is [128 rows x K], both bf16
// row-major with row strides lda/ldb. kTiles = K/32. acc indexed [mi][ni].
__device__ __forceinline__ void gemm_core(const bf16_t* __restrict__ A, int lda,
                                          const bf16_t* __restrict__ B, int ldb,
                                          int kTiles, bf16_t* As, bf16_t* Bs,
                                          f32x4 acc[4][4]) {
  int t = threadIdx.x;
  int l = t & 63;
  int w = t >> 6;
  int wr = (w >> 1) * 64;  // wave row offset in 128-tile
  int wc = (w & 1) * 64;   // wave col offset

  for (int kt = 0; kt < kTiles; ++kt) {
    __syncthreads();  // previous iteration's LDS reads done
    stage_tile(A + kt * 32, lda, As, t);
    stage_tile(B + kt * 32, ldb, Bs, t);
    __syncthreads();  // staging complete (vmcnt drained before barrier)

    bf16x8 af[4], bfr[4];
    int q = l >> 4;
#pragma unroll
    for (int i = 0; i < 4; ++i) {
      af[i] = read_frag(As, wr + i * 16 + (l & 15), q);
      bfr[i] = read_frag(Bs, wc + i * 16 + (l & 15), q);
    }
#pragma unroll
    for (int mi = 0; mi < 4; ++mi)
#pragma unroll
      for (int ni = 0; ni < 4; ++ni)
        acc[mi][ni] = __builtin_amdgcn_mfma_f32_16x16x32_bf16(
            af[mi], bfr[ni], acc[mi][ni], 0, 0, 0);
  }
}

// C/D layout (m89-verified): col = lane&15, row = (lane>>4)*4 + reg.

// ---------------------------------------------------------------------------
// Kernel 1: cast x (fp32) -> bf16, 8 elems/thread
// ---------------------------------------------------------------------------
__global__ __launch_bounds__(256) void cast_x_kernel(
    const float* __restrict__ x, bf16_t* __restrict__ xbf) {
  int i = blockIdx.x * 256 + threadIdx.x;
  const float4* xin = (const float4*)x;
  float4 a = xin[i * 2];
  float4 b = xin[i * 2 + 1];
  bf16_t tmp[8];
  tmp[0] = (bf16_t)a.x; tmp[1] = (bf16_t)a.y;
  tmp[2] = (bf16_t)a.z; tmp[3] = (bf16_t)a.w;
  tmp[4] = (bf16_t)b.x; tmp[5] = (bf16_t)b.y;
  tmp[6] = (bf16_t)b.z; tmp[7] = (bf16_t)b.w;
  *(uint4*)(xbf + (size_t)i * 8) = *(const uint4*)tmp;
}

// ---------------------------------------------------------------------------
// Kernel 2: transpose+cast the three weight matrices [C][H] -> bf16 [H][C]
// ---------------------------------------------------------------------------
__global__ __launch_bounds__(256) void transpose_w_kernel(
    const float* __restrict__ Wq, const float* __restrict__ Wk,
    const float* __restrict__ Wv, bf16_t* __restrict__ wt) {
  int z = blockIdx.z;
  const float* W = (z == 0) ? Wq : (z == 1) ? Wk : Wv;
  bf16_t* out = wt + (size_t)z * CC * CC;
  __shared__ float tile[32][33];
  int tx = threadIdx.x;  // 0..31
  int ty = threadIdx.y;  // 0..7
  int n0 = blockIdx.x * 32;
  int c0 = blockIdx.y * 32;
#pragma unroll
  for (int k = 0; k < 4; ++k)
    tile[ty + k * 8][tx] = W[(size_t)(c0 + ty + k * 8) * CC + n0 + tx];
  __syncthreads();
#pragma unroll
  for (int k = 0; k < 4; ++k)
    out[(size_t)(n0 + ty + k * 8) * CC + c0 + tx] =
        (bf16_t)tile[tx][ty + k * 8];
}

// ---------------------------------------------------------------------------
// Kernel 3: QKV GEMM.  z=0: q (scaled by H^-1/2), z=1: k, z=2: v transposed.
// ---------------------------------------------------------------------------
__global__ __launch_bounds__(256) void qkv_gemm_kernel(
    const bf16_t* __restrict__ xbf, const bf16_t* __restrict__ wt,
    const float* __restrict__ bq, const float* __restrict__ bk,
    const float* __restrict__ bv, bf16_t* __restrict__ qb,
    bf16_t* __restrict__ kb, bf16_t* __restrict__ vt) {
  __shared__ bf16_t As[128 * 32];
  __shared__ bf16_t Bs[128 * 32];
  int n0 = blockIdx.x * 128;
  int m0 = blockIdx.y * 128;
  int z = blockIdx.z;

  f32x4 acc[4][4];
#pragma unroll
  for (int i = 0; i < 4; ++i)
#pragma unroll
    for (int j = 0; j < 4; ++j) acc[i][j] = (f32x4){0.f, 0.f, 0.f, 0.f};

  const bf16_t* A = xbf + (size_t)m0 * CC;
  const bf16_t* B = wt + (size_t)z * CC * CC + (size_t)n0 * CC;
  gemm_core(A, CC, B, CC, CC / 32, As, Bs, acc);

  int l = threadIdx.x & 63, w = threadIdx.x >> 6;
  int wr = (w >> 1) * 64, wc = (w & 1) * 64;
  const float* bias = (z == 0) ? bq : (z == 1) ? bk : bv;
  float scale = (z == 0) ? rsqrtf((float)CC) : 1.0f;

#pragma unroll
  for (int mi = 0; mi < 4; ++mi) {
#pragma unroll
    for (int ni = 0; ni < 4; ++ni) {
      int col = n0 + wc + ni * 16 + (l & 15);
      int rbase = m0 + wr + mi * 16 + (l >> 4) * 4;
      float bcol = bias[col];
#pragma unroll
      for (int r = 0; r < 4; ++r) {
        int m = rbase + r;
        float v = (acc[mi][ni][r] + bcol) * scale;
        bf16_t h = (bf16_t)v;
        if (z == 0) {
          qb[(size_t)m * CC + col] = h;
        } else if (z == 1) {
          kb[(size_t)m * CC + col] = h;
        } else {
          int b = m >> 11, tt = m & (TT - 1);
          vt[((size_t)b * CC + col) * TT + tt] = h;  // v^T: [B][H][T]
        }
      }
    }
  }
}

// ---------------------------------------------------------------------------
// Kernel 4: S = q k^T (scale folded into q), causal mask + (==0 -> -inf)
// Only lower-triangular 128x128 blocks computed.
// ---------------------------------------------------------------------------
__global__ __launch_bounds__(256) void s_gemm_kernel(
    const bf16_t* __restrict__ qb, const bf16_t* __restrict__ kb,
    float* __restrict__ S) {
  int tj = blockIdx.x, ti = blockIdx.y, b = blockIdx.z;
  if (tj > ti) return;
  __shared__ bf16_t As[128 * 32];
  __shared__ bf16_t Bs[128 * 32];
  int m0 = ti * 128, n0 = tj * 128;

  f32x4 acc[4][4];
#pragma unroll
  for (int i = 0; i < 4; ++i)
#pragma unroll
    for (int j = 0; j < 4; ++j) acc[i][j] = (f32x4){0.f, 0.f, 0.f, 0.f};

  const bf16_t* A = qb + ((size_t)b * TT + m0) * CC;
  const bf16_t* B = kb + ((size_t)b * TT + n0) * CC;
  gemm_core(A, CC, B, CC, CC / 32, As, Bs, acc);

  float* Sb = S + (size_t)b * TT * TT;
  int l = threadIdx.x & 63, w = threadIdx.x >> 6;
  int wr = (w >> 1) * 64, wc = (w & 1) * 64;
#pragma unroll
  for (int mi = 0; mi < 4; ++mi) {
#pragma unroll
    for (int ni = 0; ni < 4; ++ni) {
      int j = n0 + wc + ni * 16 + (l & 15);
      int ibase = m0 + wr + mi * 16 + (l >> 4) * 4;
#pragma unroll
      for (int r = 0; r < 4; ++r) {
        int i = ibase + r;
        float v = acc[mi][ni][r];
        if (j > i || v == 0.0f) v = -INFINITY;  // causal + reference quirk
        Sb[(size_t)i * TT + j] = v;
      }
    }
  }
}

// ---------------------------------------------------------------------------
// Kernel 5: row softmax over causal length, write P bf16 zero-padded to the
// next 128 boundary (exactly what o_gemm reads).
// ---------------------------------------------------------------------------
__global__ __launch_bounds__(256) void softmax_kernel(
    const float* __restrict__ S, bf16_t* __restrict__ P) {
  int row = blockIdx.x & (TT - 1);
  int b = blockIdx.x >> 11;
  const float* s = S + ((size_t)b * TT + row) * TT;
  bf16_t* p = P + ((size_t)b * TT + row) * TT;
  int len = row + 1;
  int pe = ((row >> 7) + 1) << 7;  // pad end

  float m = -INFINITY;
  for (int j = threadIdx.x; j < len; j += 256) m = fmaxf(m, s[j]);
#pragma unroll
  for (int off = 32; off > 0; off >>= 1) m = fmaxf(m, __shfl_xor(m, off));
  __shared__ float redm[4];
  int w = threadIdx.x >> 6, l = threadIdx.x & 63;
  if (l == 0) redm[w] = m;
  __syncthreads();
  m = fmaxf(fmaxf(redm[0], redm[1]), fmaxf(redm[2], redm[3]));

  float sum = 0.f;
  for (int j = threadIdx.x; j < len; j += 256) sum += expf(s[j] - m);
#pragma unroll
  for (int off = 32; off > 0; off >>= 1) sum += __shfl_xor(sum, off);
  __shared__ float reds[4];
  if (l == 0) reds[w] = sum;
  __syncthreads();
  sum = reds[0] + reds[1] + reds[2] + reds[3];
  float inv = 1.0f / sum;

  for (int j = threadIdx.x; j < pe; j += 256) {
    float v = (j < len) ? expf(s[j] - m) * inv : 0.f;
    p[j] = (bf16_t)v;
  }
}

// ---------------------------------------------------------------------------
// Kernel 6: O = P @ V   (A = P row-major [T][T], Bt = v^T [H][T])
// K-loop truncated at the causal boundary: k < (ti+1)*128.
// ---------------------------------------------------------------------------
__global__ __launch_bounds__(256) void o_gemm_kernel(
    const bf16_t* __restrict__ P, const bf16_t* __restrict__ vt,
    float* __restrict__ out) {
  int nj = blockIdx.x, ti = blockIdx.y, b = blockIdx.z;
  __shared__ bf16_t As[128 * 32];
  __shared__ bf16_t Bs[128 * 32];
  int m0 = ti * 128, n0 = nj * 128;

  f32x4 acc[4][4];
#pragma unroll
  for (int i = 0; i < 4; ++i)
#pragma unroll
    for (int j = 0; j < 4; ++j) acc[i][j] = (f32x4){0.f, 0.f, 0.f, 0.f};

  const bf16_t* A = P + ((size_t)b * TT + m0) * TT;
  const bf16_t* B = vt + ((size_t)b * CC + n0) * TT;
  gemm_core(A, TT, B, TT, (ti + 1) * 4, As, Bs, acc);

  float* Ob = out + (size_t)b * TT * CC;
  int l = threadIdx.x & 63, w = threadIdx.x >> 6;
  int wr = (w >> 1) * 64, wc = (w & 1) * 64;
#pragma unroll
  for (int mi = 0; mi < 4; ++mi) {
#pragma unroll
    for (int ni = 0; ni < 4; ++ni) {
      int col = n0 + wc + ni * 16 + (l & 15);
      int ibase = m0 + wr + mi * 16 + (l >> 4) * 4;
#pragma unroll
      for (int r = 0; r < 4; ++r)
        Ob[(size_t)(ibase + r) * CC + col] = acc[mi][ni][r];
    }
  }
}

// ---------------------------------------------------------------------------
extern "C" void kernel_launch(void* const* d_in, const int* in_sizes, int n_in,
                              void* d_out, int out_size, void* d_ws,
                              size_t ws_size, hipStream_t stream) {
  const float* x = (const float*)d_in[0];
  const float* Wq = (const float*)d_in[1];
  const float* bq = (const float*)d_in[2];
  const float* Wk = (const float*)d_in[3];
  const float* bk = (const float*)d_in[4];
  const float* Wv = (const float*)d_in[5];
  const float* bv = (const float*)d_in[6];
  float* out = (float*)d_out;

  char* ws = (char*)d_ws;
  size_t off = 0;
  auto carve = [&](size_t bytes) -> char* {
    char* p = ws + off;
    off += (bytes + 255) & ~(size_t)255;
    return p;
  };
  const size_t M = (size_t)BB * TT;  // 8192
  bf16_t* xbf = (bf16_t*)carve(M * CC * 2);            // 12.6 MB
  bf16_t* wt  = (bf16_t*)carve(3ull * CC * CC * 2);    // 3.5 MB
  bf16_t* qb  = (bf16_t*)carve(M * CC * 2);            // 12.6 MB
  bf16_t* kb  = (bf16_t*)carve(M * CC * 2);            // 12.6 MB
  bf16_t* vt  = (bf16_t*)carve(M * CC * 2);            // 12.6 MB (as [B][H][T])
  float*  S   = (float*)carve((size_t)BB * TT * TT * 4);   // 67 MB
  bf16_t* P   = (bf16_t*)carve((size_t)BB * TT * TT * 2);  // 33.5 MB
  (void)off; (void)ws_size;

  // 1+2: input prep
  cast_x_kernel<<<(M * CC / 8 + 255) / 256, 256, 0, stream>>>(x, xbf);
  transpose_w_kernel<<<dim3(CC / 32, CC / 32, 3), dim3(32, 8, 1), 0, stream>>>(
      Wq, Wk, Wv, wt);
  // 3: q,k,v
  qkv_gemm_kernel<<<dim3(CC / 128, M / 128, 3), 256, 0, stream>>>(
      xbf, wt, bq, bk, bv, qb, kb, vt);
  // 4: S = q k^T (lower-tri blocks)
  s_gemm_kernel<<<dim3(TT / 128, TT / 128, BB), 256, 0, stream>>>(qb, kb, S);
  // 5: softmax rows -> P (bf16, zero-padded)
  softmax_kernel<<<BB * TT, 256, 0, stream>>>(S, P);
  // 6: O = P V
  o_gemm_kernel<<<dim3(CC / 128, TT / 128, BB), 256, 0, stream>>>(P, vt, out);
}